// Round 7
// baseline (200.713 us; speedup 1.0000x reference)
//
#include <hip/hip_runtime.h>
#include <stdint.h>

typedef __bf16 bf16x8 __attribute__((ext_vector_type(8)));
typedef float f32x4 __attribute__((ext_vector_type(4)));

#define B_ 16
#define C_ 512
#define S_ 1024   // W*H = 32*32
#define N1 1536   // 3C

// ---------- bf16 helpers (manual RNE) ----------
__device__ inline unsigned short f2b(float f) {
    unsigned int u = __builtin_bit_cast(unsigned int, f);
    unsigned int lsb = (u >> 16) & 1u;
    u += 0x7fffu + lsb;
    return (unsigned short)(u >> 16);
}
__device__ inline float b2f(unsigned int s) {
    unsigned int u = (s & 0xffffu) << 16;
    return __builtin_bit_cast(float, u);
}

// async global->LDS, 16B per lane. LDS dest must be wave-uniform base + lane*16.
__device__ inline void gl_lds16(const unsigned short* g, unsigned short* l) {
    __builtin_amdgcn_global_load_lds(
        (const __attribute__((address_space(1))) void*)(g),
        (__attribute__((address_space(3))) void*)(l),
        16, 0, 0);
}

// ---------- K1: transpose_convert_x + weight convert + sums zero (merged) ----------
// blocks [0,8192): x (B,C,S) f32 -> xT (B,S,C) bf16, 32x32 tiles
// blocks [8192,9336): w1/w2 f32->bf16 (float4-granular) + zero sum planes
__global__ __launch_bounds__(256) void prep_all(
    const float* __restrict__ x, unsigned short* __restrict__ xT,
    const float* __restrict__ w1, const float* __restrict__ w2,
    unsigned short* __restrict__ w1b, unsigned short* __restrict__ w2b,
    float* __restrict__ sums)
{
    int bid = blockIdx.x;
    int t = threadIdx.x;
    if (bid < 8192) {
        __shared__ float tile[32][33];
        int bx = bid & 31;          // s-tile
        int by = (bid >> 5) & 15;   // c-tile
        int bz = bid >> 9;          // batch
        int c0 = by * 32;
        int s0 = bx * 32;
        int tx = t & 31, ty = t >> 5; // (32,8)
        const float* xp = x + ((size_t)bz * C_ + c0) * S_ + s0;
#pragma unroll
        for (int i = 0; i < 4; i++)
            tile[ty + i * 8][tx] = xp[(size_t)(ty + i * 8) * S_ + tx];
        __syncthreads();
        unsigned short* op = xT + ((size_t)bz * S_ + s0) * C_ + c0;
#pragma unroll
        for (int i = 0; i < 4; i++)
            op[(size_t)(ty + i * 8) * C_ + tx] = f2b(tile[tx][ty + i * 8]);
    } else {
        int i = (bid - 8192) * 256 + t;
        if (i < 196608) {
            float4 v = ((const float4*)w1)[i];
            ((ushort4*)w1b)[i] = make_ushort4(f2b(v.x), f2b(v.y), f2b(v.z), f2b(v.w));
        } else if (i < 262144) {
            int j = i - 196608;
            float4 v = ((const float4*)w2)[j];
            ((ushort4*)w2b)[j] = make_ushort4(f2b(v.x), f2b(v.y), f2b(v.z), f2b(v.w));
        } else if (i < 292864) {
            int j = i - 262144;
            ((float4*)sums)[j] = make_float4(0.f, 0.f, 0.f, 0.f);
        }
    }
}

// shift tables per quarter q = c>>7:
// x1: dw = {-1,+1,0,0}[q], dh = {0,0,-1,+1}[q]   (channels [0,512) of y)
// x2: dh = {-1,+1,0,0}[q], dw = {0,0,-1,+1}[q]   (channels [512,1024))
// x3: no shift                                    (channels [1024,1536))

// ---------- K2: GEMM1 y = xT . w1^T + b1, with fused a-sum planes ----------
// R4-proven: 128x128 tile, single-buffer, global_load_lds width-16, 64B LDS rows.
__global__ __launch_bounds__(256) void gemm1(
    const unsigned short* __restrict__ A,
    const unsigned short* __restrict__ Wt,
    const float* __restrict__ bias,
    unsigned short* __restrict__ Y,
    float* __restrict__ Tsum, float* __restrict__ H0, float* __restrict__ H31,
    float* __restrict__ C0, float* __restrict__ C31)
{
    const int K = 512;
    const int N = 1536;
    __shared__ __align__(16) unsigned short As[128 * 32]; // 8 KB, 64B rows
    __shared__ __align__(16) unsigned short Bs[128 * 32];
    int m0 = blockIdx.x * 128;
    int n0 = blockIdx.y * 128;
    int tid = threadIdx.x;
    int lane = tid & 63, wid = tid >> 6;
    int wm = (wid >> 1) * 64, wn = (wid & 1) * 64;
    int quad = lane >> 4, l16 = lane & 15;
    int ch0 = wid * 128 + lane;
    const unsigned short* Ab = A + (size_t)m0 * K;
    const unsigned short* Bb = Wt + (size_t)n0 * K;

    f32x4 acc[4][4] = {};

    for (int kt = 0; kt < K; kt += 32) {
        __syncthreads();
#pragma unroll
        for (int i = 0; i < 2; i++) {
            int ch = ch0 + i * 64;
            int m = ch >> 2, kc = ch & 3;
            size_t go = (size_t)m * K + kt + kc * 8;
            gl_lds16(Ab + go, &As[ch * 8]);
            gl_lds16(Bb + go, &Bs[ch * 8]);
        }
        __syncthreads();
        bf16x8 af[4], bfr[4];
#pragma unroll
        for (int t = 0; t < 4; t++) {
            af[t]  = *(const bf16x8*)&As[(wm + t * 16 + l16) * 32 + quad * 8];
            bfr[t] = *(const bf16x8*)&Bs[(wn + t * 16 + l16) * 32 + quad * 8];
        }
#pragma unroll
        for (int mt = 0; mt < 4; mt++)
#pragma unroll
            for (int nt = 0; nt < 4; nt++)
                acc[mt][nt] = __builtin_amdgcn_mfma_f32_16x16x32_bf16(af[mt], bfr[nt], acc[mt][nt], 0, 0, 0);
    }

    // ---- write y (bf16) ----
#pragma unroll
    for (int mt = 0; mt < 4; mt++) {
#pragma unroll
        for (int nt = 0; nt < 4; nt++) {
            int n = n0 + wn + nt * 16 + l16;
            float bv = bias[n];
            int mbase = m0 + wm + mt * 16 + quad * 4;
#pragma unroll
            for (int r = 0; r < 4; r++)
                Y[(size_t)(mbase + r) * N + n] = f2b(acc[mt][nt][r] + bv);
        }
    }

    // ---- fused a-sum accumulators ----
    // m_local = wm + mt*16 + quad*4 + r; h = m_local&31; w = wlo + (m_local>>5)
    {
        int b = m0 >> 10;
        int wlo = (m0 & 1023) >> 5; // first of 4 w-rows in this block
#pragma unroll
        for (int nt = 0; nt < 4; nt++) {
            int n = n0 + wn + nt * 16 + l16;
            float bv = bias[n];
            float tT = 0.f;
#pragma unroll
            for (int mt = 0; mt < 4; mt++)
#pragma unroll
                for (int r = 0; r < 4; r++) tT += acc[mt][nt][r] + bv;
            tT += __shfl_xor(tT, 16);
            tT += __shfl_xor(tT, 32);
            if (quad == 0) {
                atomicAdd(&Tsum[b * 1536 + n], tT);
                float th0 = acc[0][nt][0] + acc[2][nt][0] + 2.f * bv; // h==0 rows
                atomicAdd(&H0[b * 1536 + n], th0);
            }
            if (quad == 3) {
                float th31 = acc[1][nt][3] + acc[3][nt][3] + 2.f * bv; // h==31 rows
                atomicAdd(&H31[b * 1536 + n], th31);
            }
            if (wlo == 0 && wm == 0) { // w==0 slice: m_local < 32 -> mt 0,1
                float tc = 0.f;
#pragma unroll
                for (int mt = 0; mt < 2; mt++)
#pragma unroll
                    for (int r = 0; r < 4; r++) tc += acc[mt][nt][r] + bv;
                tc += __shfl_xor(tc, 16);
                tc += __shfl_xor(tc, 32);
                if (quad == 0) atomicAdd(&C0[b * 1536 + n], tc);
            }
            if (wlo == 28 && wm == 64) { // w==31 slice: m_local >= 96 -> mt 2,3
                float tc = 0.f;
#pragma unroll
                for (int mt = 2; mt < 4; mt++)
#pragma unroll
                    for (int r = 0; r < 4; r++) tc += acc[mt][nt][r] + bv;
                tc += __shfl_xor(tc, 16);
                tc += __shfl_xor(tc, 32);
                if (quad == 0) atomicAdd(&C31[b * 1536 + n], tc);
            }
        }
    }
}

// ---------- K3: layer1 (reconstruct a from sum planes, wave-dot, gelu) ----------
__global__ __launch_bounds__(256) void mlp_layer1(
    const float* __restrict__ sums, const float* __restrict__ wa,
    const float* __restrict__ ba, float* __restrict__ h)
{
    __shared__ float sa[512];
    int b = blockIdx.x >> 7;
    int t = threadIdx.x;
    const float* Tp   = sums;
    const float* H0p  = sums + 24576;
    const float* H31p = sums + 49152;
    const float* C0p  = sums + 73728;
    const float* C31p = sums + 98304;
#pragma unroll
    for (int j = 0; j < 2; j++) {
        int c = t + j * 256;
        int q = c >> 7;
        int n1 = b * 1536 + c;
        float t123 = Tp[n1] + Tp[n1 + 512] + Tp[n1 + 1024];
        float sC1 = C0p[n1] - C31p[n1];
        float sH1 = H0p[n1] - H31p[n1];
        float sC2 = C0p[n1 + 512] - C31p[n1 + 512];
        float sH2 = H0p[n1 + 512] - H31p[n1 + 512];
        float e = (q < 2) ? (sC1 + sH2) : (sH1 + sC2);
        sa[c] = t123 + ((q & 1) ? -e : e);
    }
    __syncthreads();
    int lane = t & 63, wid = t >> 6;
    int o = (blockIdx.x & 127) * 4 + wid;
    const float4* wr = (const float4*)(wa + (size_t)o * 512);
    float4 w0 = wr[lane * 2], w1v = wr[lane * 2 + 1];
    float4 a0 = ((const float4*)sa)[lane * 2], a1 = ((const float4*)sa)[lane * 2 + 1];
    float dot = w0.x * a0.x + w0.y * a0.y + w0.z * a0.z + w0.w * a0.w
              + w1v.x * a1.x + w1v.y * a1.y + w1v.z * a1.z + w1v.w * a1.w;
#pragma unroll
    for (int off = 32; off; off >>= 1) dot += __shfl_down(dot, off);
    if (lane == 0) {
        float v = dot + ba[o];
        h[b * 512 + o] = 0.5f * v * (1.0f + erff(v * 0.7071067811865475f));
    }
}

// ---------- K4: layer2 + softmax gate, o-major (wave owns channel c, all 16 b) ----------
// g[(b*3+j)*512 + c] = softmax_j( dot(h[b,:], wb[j*512+c,:]) + bb[j*512+c] )
__global__ __launch_bounds__(256) void mlp2_gate(
    const float* __restrict__ h, const float* __restrict__ wb,
    const float* __restrict__ bb, float* __restrict__ g)
{
    __shared__ float hat_s[4][3][16];
    int wv = threadIdx.x >> 6, lane = threadIdx.x & 63;
    int c = blockIdx.x * 4 + wv;
    float4 wr[3][2];
    float bbv[3];
#pragma unroll
    for (int j = 0; j < 3; j++) {
        const float4* p = (const float4*)(wb + (size_t)(j * 512 + c) * 512 + lane * 8);
        wr[j][0] = p[0]; wr[j][1] = p[1];
        bbv[j] = bb[j * 512 + c];
    }
    for (int b = 0; b < 16; b++) {
        const float4* hp = (const float4*)(h + b * 512 + lane * 8);
        float4 h0 = hp[0], h1 = hp[1];
        float d[3];
#pragma unroll
        for (int j = 0; j < 3; j++) {
            d[j] = wr[j][0].x * h0.x + wr[j][0].y * h0.y + wr[j][0].z * h0.z + wr[j][0].w * h0.w
                 + wr[j][1].x * h1.x + wr[j][1].y * h1.y + wr[j][1].z * h1.z + wr[j][1].w * h1.w;
#pragma unroll
            for (int off = 32; off; off >>= 1) d[j] += __shfl_down(d[j], off);
        }
        if (lane == 0) {
#pragma unroll
            for (int j = 0; j < 3; j++) hat_s[wv][j][b] = d[j] + bbv[j];
        }
    }
    __syncthreads();
    if (lane < 16) {
        int b = lane;
        float h0 = hat_s[wv][0][b], h1 = hat_s[wv][1][b], h2 = hat_s[wv][2][b];
        float mx = fmaxf(h0, fmaxf(h1, h2));
        float e0 = __expf(h0 - mx), e1 = __expf(h1 - mx), e2 = __expf(h2 - mx);
        float inv = 1.0f / (e0 + e1 + e2);
        g[(b * 3 + 0) * 512 + c] = e0 * inv;
        g[(b * 3 + 1) * 512 + c] = e1 * inv;
        g[(b * 3 + 2) * 512 + c] = e2 * inv;
    }
}

// ---------- K5: GEMM2 with combine fused into A-staging ----------
// A[m,k] = out[b,s,c] = sum_j g_j[b,c] * y_shifted_j, computed inline per K-tile.
// K-tile of 32 channels lies in one quarter -> uniform shifts.
// Output: out[(b*512+n)*1024 + s] f32, coalesced float4 along s.
__global__ __launch_bounds__(256) void gemm2_fused(
    const unsigned short* __restrict__ y,
    const float* __restrict__ g,
    const unsigned short* __restrict__ Wt,   // w2b: 512x512
    const float* __restrict__ bias,
    float* __restrict__ Z)
{
    const int K = 512;
    __shared__ __align__(16) unsigned short As[128 * 32]; // 8 KB, 64B rows
    __shared__ __align__(16) unsigned short Bs[128 * 32];
    int m0 = blockIdx.x * 128;
    int n0 = blockIdx.y * 128;
    int tid = threadIdx.x;
    int lane = tid & 63, wid = tid >> 6;
    int wm = (wid >> 1) * 64, wn = (wid & 1) * 64;
    int quad = lane >> 4, l16 = lane & 15;
    int ch0 = wid * 128 + lane;
    const unsigned short* Bb = Wt + (size_t)n0 * K;

    int b = m0 >> 10;
    // this thread's staged row: m_l = tid>>1, its 16-channel half = tid&1
    int m_l = tid >> 1;
    int half = tid & 1;
    int s = (m0 & 1023) + m_l;
    int w = s >> 5, hh = s & 31;
    size_t ybase = (size_t)b * 1024;
    const float* gA = g + (b * 3 + 0) * 512;
    const float* gB = g + (b * 3 + 1) * 512;
    const float* gC = g + (b * 3 + 2) * 512;

    f32x4 acc[4][4] = {};

    for (int kt = 0; kt < K; kt += 32) {
        __syncthreads();
        // --- B: global_load_lds staging (same as gemm1) ---
#pragma unroll
        for (int i = 0; i < 2; i++) {
            int ch = ch0 + i * 64;
            int m = ch >> 2, kc = ch & 3;
            gl_lds16(Bb + (size_t)m * K + kt + kc * 8, &Bs[ch * 8]);
        }
        // --- A: compute combine inline, ds_write_b128 x2 ---
        {
            int q = kt >> 7;
            int dw1 = (q == 0) ? -1 : (q == 1) ? 1 : 0;
            int dh1 = (q == 2) ? -1 : (q == 3) ? 1 : 0;
            int dh2 = (q == 0) ? -1 : (q == 1) ? 1 : 0;
            int dw2 = (q == 2) ? -1 : (q == 3) ? 1 : 0;
            int w1i = min(max(w + dw1, 0), 31), h1i = min(max(hh + dh1, 0), 31);
            int w2i = min(max(w + dw2, 0), 31), h2i = min(max(hh + dh2, 0), 31);
            const unsigned short* y1p = y + (ybase + w1i * 32 + h1i) * N1 + kt;
            const unsigned short* y2p = y + (ybase + w2i * 32 + h2i) * N1 + 512 + kt;
            const unsigned short* y3p = y + (ybase + w * 32 + hh) * N1 + 1024 + kt;
            int c0 = half * 16;
#pragma unroll
            for (int cc = 0; cc < 2; cc++) {
                int cb = c0 + cc * 8;
                uint4 u1 = *(const uint4*)(y1p + cb);
                uint4 u2 = *(const uint4*)(y2p + cb);
                uint4 u3 = *(const uint4*)(y3p + cb);
                float4 ga0 = *(const float4*)(gA + kt + cb), ga1 = *(const float4*)(gA + kt + cb + 4);
                float4 gb0 = *(const float4*)(gB + kt + cb), gb1 = *(const float4*)(gB + kt + cb + 4);
                float4 gc0 = *(const float4*)(gC + kt + cb), gc1 = *(const float4*)(gC + kt + cb + 4);
                const unsigned int* a1 = &u1.x;
                const unsigned int* a2 = &u2.x;
                const unsigned int* a3 = &u3.x;
                const float* pga[2] = { &ga0.x, &ga1.x };
                const float* pgb[2] = { &gb0.x, &gb1.x };
                const float* pgc[2] = { &gc0.x, &gc1.x };
                unsigned int pk[4];
#pragma unroll
                for (int k4 = 0; k4 < 4; k4++) {
                    int gi = k4 >> 1, go_ = (k4 & 1) * 2;
                    float lo = pga[gi][go_]     * b2f(a1[k4])       + pgb[gi][go_]     * b2f(a2[k4])       + pgc[gi][go_]     * b2f(a3[k4]);
                    float hi = pga[gi][go_ + 1] * b2f(a1[k4] >> 16) + pgb[gi][go_ + 1] * b2f(a2[k4] >> 16) + pgc[gi][go_ + 1] * b2f(a3[k4] >> 16);
                    pk[k4] = (unsigned int)f2b(lo) | ((unsigned int)f2b(hi) << 16);
                }
                *(uint4*)&As[m_l * 32 + cb] = make_uint4(pk[0], pk[1], pk[2], pk[3]);
            }
        }
        __syncthreads();
        bf16x8 af[4], bfr[4];
#pragma unroll
        for (int t = 0; t < 4; t++) {
            af[t]  = *(const bf16x8*)&As[(wm + t * 16 + l16) * 32 + quad * 8];
            bfr[t] = *(const bf16x8*)&Bs[(wn + t * 16 + l16) * 32 + quad * 8];
        }
#pragma unroll
        for (int mt = 0; mt < 4; mt++)
#pragma unroll
            for (int nt = 0; nt < 4; nt++)
                acc[mt][nt] = __builtin_amdgcn_mfma_f32_16x16x32_bf16(af[mt], bfr[nt], acc[mt][nt], 0, 0, 0);
    }

    // ---- transposed f32 epilogue: out[(b*512+n)*1024 + s], float4 along s ----
#pragma unroll
    for (int mt = 0; mt < 4; mt++) {
#pragma unroll
        for (int nt = 0; nt < 4; nt++) {
            int n = n0 + wn + nt * 16 + l16;
            float bv = bias[n];
            int mbase = m0 + wm + mt * 16 + quad * 4;
            int bb_ = mbase >> 10;
            int ss = mbase & 1023;
            float4 v = make_float4(acc[mt][nt][0] + bv, acc[mt][nt][1] + bv,
                                   acc[mt][nt][2] + bv, acc[mt][nt][3] + bv);
            *(float4*)(&Z[((size_t)(bb_ * 512 + n)) * 1024 + ss]) = v;
        }
    }
}

extern "C" void kernel_launch(void* const* d_in, const int* in_sizes, int n_in,
                              void* d_out, int out_size, void* d_ws, size_t ws_size,
                              hipStream_t stream) {
    const float* x  = (const float*)d_in[0];
    const float* w1 = (const float*)d_in[1];
    const float* b1 = (const float*)d_in[2];
    const float* wa = (const float*)d_in[3];
    const float* ba = (const float*)d_in[4];
    const float* wb = (const float*)d_in[5];
    const float* bb = (const float*)d_in[6];
    const float* w2 = (const float*)d_in[7];
    const float* b2 = (const float*)d_in[8];
    float* out = (float*)d_out;

    char* ws = (char*)d_ws;
    unsigned short* xT   = (unsigned short*)(ws);              // 16 MB
    unsigned short* w1b  = (unsigned short*)(ws + 16777216);   // 1.5 MB
    unsigned short* w2b  = (unsigned short*)(ws + 18350080);   // 0.5 MB
    unsigned short* y    = (unsigned short*)(ws + 18874368);   // 48 MB: (B,S,3C) bf16
    float* sums          = (float*)(ws + 69206016);            // 5 x 96 KB: T,H0,H31,C0,C31
    float* h_buf         = (float*)(ws + 69697536);            // 32 KB
    float* g_buf         = (float*)(ws + 69730304);            // 96 KB: (16,3,512) f32

    float* Tsum = sums;
    float* H0   = sums + 24576;
    float* H31  = sums + 49152;
    float* C0   = sums + 73728;
    float* C31  = sums + 98304;

    prep_all<<<dim3(9336), dim3(256), 0, stream>>>(x, xT, w1, w2, w1b, w2b, sums);
    gemm1<<<dim3(128, 12), dim3(256), 0, stream>>>(
        xT, w1b, b1, y, Tsum, H0, H31, C0, C31);
    mlp_layer1<<<dim3(2048), dim3(256), 0, stream>>>(sums, wa, ba, h_buf);
    mlp2_gate<<<dim3(128), dim3(256), 0, stream>>>(h_buf, wb, bb, g_buf);
    gemm2_fused<<<dim3(128, 4), dim3(256), 0, stream>>>(y, g_buf, w2b, b2, out);
}

// Round 8
// 197.161 us; speedup vs baseline: 1.0180x; 1.0180x over previous
//
#include <hip/hip_runtime.h>
#include <stdint.h>

typedef __bf16 bf16x8 __attribute__((ext_vector_type(8)));
typedef float f32x4 __attribute__((ext_vector_type(4)));

#define B_ 16
#define C_ 512
#define S_ 1024   // W*H = 32*32
#define N1 1536   // 3C

// ---------- bf16 helpers (manual RNE) ----------
__device__ inline unsigned short f2b(float f) {
    unsigned int u = __builtin_bit_cast(unsigned int, f);
    unsigned int lsb = (u >> 16) & 1u;
    u += 0x7fffu + lsb;
    return (unsigned short)(u >> 16);
}
__device__ inline float b2f(unsigned int s) {
    unsigned int u = (s & 0xffffu) << 16;
    return __builtin_bit_cast(float, u);
}

// async global->LDS, 16B per lane. LDS dest must be wave-uniform base + lane*16.
__device__ inline void gl_lds16(const unsigned short* g, unsigned short* l) {
    __builtin_amdgcn_global_load_lds(
        (const __attribute__((address_space(1))) void*)(g),
        (__attribute__((address_space(3))) void*)(l),
        16, 0, 0);
}

// ---------- K1: transpose_convert_x + weight convert + sums zero (merged) ----------
__global__ __launch_bounds__(256) void prep_all(
    const float* __restrict__ x, unsigned short* __restrict__ xT,
    const float* __restrict__ w1, const float* __restrict__ w2,
    unsigned short* __restrict__ w1b, unsigned short* __restrict__ w2b,
    float* __restrict__ sums)
{
    int bid = blockIdx.x;
    int t = threadIdx.x;
    if (bid < 8192) {
        __shared__ float tile[32][33];
        int bx = bid & 31;          // s-tile
        int by = (bid >> 5) & 15;   // c-tile
        int bz = bid >> 9;          // batch
        int c0 = by * 32;
        int s0 = bx * 32;
        int tx = t & 31, ty = t >> 5; // (32,8)
        const float* xp = x + ((size_t)bz * C_ + c0) * S_ + s0;
#pragma unroll
        for (int i = 0; i < 4; i++)
            tile[ty + i * 8][tx] = xp[(size_t)(ty + i * 8) * S_ + tx];
        __syncthreads();
        unsigned short* op = xT + ((size_t)bz * S_ + s0) * C_ + c0;
#pragma unroll
        for (int i = 0; i < 4; i++)
            op[(size_t)(ty + i * 8) * C_ + tx] = f2b(tile[tx][ty + i * 8]);
    } else {
        int i = (bid - 8192) * 256 + t;
        if (i < 196608) {
            float4 v = ((const float4*)w1)[i];
            ((ushort4*)w1b)[i] = make_ushort4(f2b(v.x), f2b(v.y), f2b(v.z), f2b(v.w));
        } else if (i < 262144) {
            int j = i - 196608;
            float4 v = ((const float4*)w2)[j];
            ((ushort4*)w2b)[j] = make_ushort4(f2b(v.x), f2b(v.y), f2b(v.z), f2b(v.w));
        } else if (i < 292864) {
            int j = i - 262144;
            ((float4*)sums)[j] = make_float4(0.f, 0.f, 0.f, 0.f);
        }
    }
}

// shift tables per quarter q = c>>7:
// x1: dw = {-1,+1,0,0}[q], dh = {0,0,-1,+1}[q]   (channels [0,512) of y)
// x2: dh = {-1,+1,0,0}[q], dw = {0,0,-1,+1}[q]   (channels [512,1024))
// x3: no shift                                    (channels [1024,1536))

// ---------- K2: GEMM1 y = xT . w1^T + b1, with fused a-sum planes ----------
// R4-proven: 128x128 tile, single-buffer, global_load_lds width-16, 64B LDS rows.
__global__ __launch_bounds__(256) void gemm1(
    const unsigned short* __restrict__ A,
    const unsigned short* __restrict__ Wt,
    const float* __restrict__ bias,
    unsigned short* __restrict__ Y,
    float* __restrict__ Tsum, float* __restrict__ H0, float* __restrict__ H31,
    float* __restrict__ C0, float* __restrict__ C31)
{
    const int K = 512;
    const int N = 1536;
    __shared__ __align__(16) unsigned short As[128 * 32]; // 8 KB, 64B rows
    __shared__ __align__(16) unsigned short Bs[128 * 32];
    int m0 = blockIdx.x * 128;
    int n0 = blockIdx.y * 128;
    int tid = threadIdx.x;
    int lane = tid & 63, wid = tid >> 6;
    int wm = (wid >> 1) * 64, wn = (wid & 1) * 64;
    int quad = lane >> 4, l16 = lane & 15;
    int ch0 = wid * 128 + lane;
    const unsigned short* Ab = A + (size_t)m0 * K;
    const unsigned short* Bb = Wt + (size_t)n0 * K;

    f32x4 acc[4][4] = {};

    for (int kt = 0; kt < K; kt += 32) {
        __syncthreads();
#pragma unroll
        for (int i = 0; i < 2; i++) {
            int ch = ch0 + i * 64;
            int m = ch >> 2, kc = ch & 3;
            size_t go = (size_t)m * K + kt + kc * 8;
            gl_lds16(Ab + go, &As[ch * 8]);
            gl_lds16(Bb + go, &Bs[ch * 8]);
        }
        __syncthreads();
        bf16x8 af[4], bfr[4];
#pragma unroll
        for (int t = 0; t < 4; t++) {
            af[t]  = *(const bf16x8*)&As[(wm + t * 16 + l16) * 32 + quad * 8];
            bfr[t] = *(const bf16x8*)&Bs[(wn + t * 16 + l16) * 32 + quad * 8];
        }
#pragma unroll
        for (int mt = 0; mt < 4; mt++)
#pragma unroll
            for (int nt = 0; nt < 4; nt++)
                acc[mt][nt] = __builtin_amdgcn_mfma_f32_16x16x32_bf16(af[mt], bfr[nt], acc[mt][nt], 0, 0, 0);
    }

    // ---- write y (bf16) ----
#pragma unroll
    for (int mt = 0; mt < 4; mt++) {
#pragma unroll
        for (int nt = 0; nt < 4; nt++) {
            int n = n0 + wn + nt * 16 + l16;
            float bv = bias[n];
            int mbase = m0 + wm + mt * 16 + quad * 4;
#pragma unroll
            for (int r = 0; r < 4; r++)
                Y[(size_t)(mbase + r) * N + n] = f2b(acc[mt][nt][r] + bv);
        }
    }

    // ---- fused a-sum accumulators ----
    // m_local = wm + mt*16 + quad*4 + r; h = m_local&31; w = wlo + (m_local>>5)
    {
        int b = m0 >> 10;
        int wlo = (m0 & 1023) >> 5; // first of 4 w-rows in this block
#pragma unroll
        for (int nt = 0; nt < 4; nt++) {
            int n = n0 + wn + nt * 16 + l16;
            float bv = bias[n];
            float tT = 0.f;
#pragma unroll
            for (int mt = 0; mt < 4; mt++)
#pragma unroll
                for (int r = 0; r < 4; r++) tT += acc[mt][nt][r] + bv;
            tT += __shfl_xor(tT, 16);
            tT += __shfl_xor(tT, 32);
            if (quad == 0) {
                atomicAdd(&Tsum[b * 1536 + n], tT);
                float th0 = acc[0][nt][0] + acc[2][nt][0] + 2.f * bv; // h==0 rows
                atomicAdd(&H0[b * 1536 + n], th0);
            }
            if (quad == 3) {
                float th31 = acc[1][nt][3] + acc[3][nt][3] + 2.f * bv; // h==31 rows
                atomicAdd(&H31[b * 1536 + n], th31);
            }
            if (wlo == 0 && wm == 0) { // w==0 slice: m_local < 32 -> mt 0,1
                float tc = 0.f;
#pragma unroll
                for (int mt = 0; mt < 2; mt++)
#pragma unroll
                    for (int r = 0; r < 4; r++) tc += acc[mt][nt][r] + bv;
                tc += __shfl_xor(tc, 16);
                tc += __shfl_xor(tc, 32);
                if (quad == 0) atomicAdd(&C0[b * 1536 + n], tc);
            }
            if (wlo == 28 && wm == 64) { // w==31 slice: m_local >= 96 -> mt 2,3
                float tc = 0.f;
#pragma unroll
                for (int mt = 2; mt < 4; mt++)
#pragma unroll
                    for (int r = 0; r < 4; r++) tc += acc[mt][nt][r] + bv;
                tc += __shfl_xor(tc, 16);
                tc += __shfl_xor(tc, 32);
                if (quad == 0) atomicAdd(&C31[b * 1536 + n], tc);
            }
        }
    }
}

// ---------- K3: layer1 (reconstruct a from sum planes, wave-dot, gelu) ----------
__global__ __launch_bounds__(256) void mlp_layer1(
    const float* __restrict__ sums, const float* __restrict__ wa,
    const float* __restrict__ ba, float* __restrict__ h)
{
    __shared__ float sa[512];
    int b = blockIdx.x >> 7;
    int t = threadIdx.x;
    const float* Tp   = sums;
    const float* H0p  = sums + 24576;
    const float* H31p = sums + 49152;
    const float* C0p  = sums + 73728;
    const float* C31p = sums + 98304;
#pragma unroll
    for (int j = 0; j < 2; j++) {
        int c = t + j * 256;
        int q = c >> 7;
        int n1 = b * 1536 + c;
        float t123 = Tp[n1] + Tp[n1 + 512] + Tp[n1 + 1024];
        float sC1 = C0p[n1] - C31p[n1];
        float sH1 = H0p[n1] - H31p[n1];
        float sC2 = C0p[n1 + 512] - C31p[n1 + 512];
        float sH2 = H0p[n1 + 512] - H31p[n1 + 512];
        float e = (q < 2) ? (sC1 + sH2) : (sH1 + sC2);
        sa[c] = t123 + ((q & 1) ? -e : e);
    }
    __syncthreads();
    int lane = t & 63, wid = t >> 6;
    int o = (blockIdx.x & 127) * 4 + wid;
    const float4* wr = (const float4*)(wa + (size_t)o * 512);
    float4 w0 = wr[lane * 2], w1v = wr[lane * 2 + 1];
    float4 a0 = ((const float4*)sa)[lane * 2], a1 = ((const float4*)sa)[lane * 2 + 1];
    float dot = w0.x * a0.x + w0.y * a0.y + w0.z * a0.z + w0.w * a0.w
              + w1v.x * a1.x + w1v.y * a1.y + w1v.z * a1.z + w1v.w * a1.w;
#pragma unroll
    for (int off = 32; off; off >>= 1) dot += __shfl_down(dot, off);
    if (lane == 0) {
        float v = dot + ba[o];
        h[b * 512 + o] = 0.5f * v * (1.0f + erff(v * 0.7071067811865475f));
    }
}

// ---------- K4: layer2 + softmax gate, o-major (wave owns channel c, all 16 b) ----------
__global__ __launch_bounds__(256) void mlp2_gate(
    const float* __restrict__ h, const float* __restrict__ wb,
    const float* __restrict__ bb, float* __restrict__ g)
{
    __shared__ float hat_s[4][3][16];
    int wv = threadIdx.x >> 6, lane = threadIdx.x & 63;
    int c = blockIdx.x * 4 + wv;
    float4 wr[3][2];
    float bbv[3];
#pragma unroll
    for (int j = 0; j < 3; j++) {
        const float4* p = (const float4*)(wb + (size_t)(j * 512 + c) * 512 + lane * 8);
        wr[j][0] = p[0]; wr[j][1] = p[1];
        bbv[j] = bb[j * 512 + c];
    }
    for (int b = 0; b < 16; b++) {
        const float4* hp = (const float4*)(h + b * 512 + lane * 8);
        float4 h0 = hp[0], h1 = hp[1];
        float d[3];
#pragma unroll
        for (int j = 0; j < 3; j++) {
            d[j] = wr[j][0].x * h0.x + wr[j][0].y * h0.y + wr[j][0].z * h0.z + wr[j][0].w * h0.w
                 + wr[j][1].x * h1.x + wr[j][1].y * h1.y + wr[j][1].z * h1.z + wr[j][1].w * h1.w;
#pragma unroll
            for (int off = 32; off; off >>= 1) d[j] += __shfl_down(d[j], off);
        }
        if (lane == 0) {
#pragma unroll
            for (int j = 0; j < 3; j++) hat_s[wv][j][b] = d[j] + bbv[j];
        }
    }
    __syncthreads();
    if (lane < 16) {
        int b = lane;
        float h0 = hat_s[wv][0][b], h1 = hat_s[wv][1][b], h2 = hat_s[wv][2][b];
        float mx = fmaxf(h0, fmaxf(h1, h2));
        float e0 = __expf(h0 - mx), e1 = __expf(h1 - mx), e2 = __expf(h2 - mx);
        float inv = 1.0f / (e0 + e1 + e2);
        g[(b * 3 + 0) * 512 + c] = e0 * inv;
        g[(b * 3 + 1) * 512 + c] = e1 * inv;
        g[(b * 3 + 2) * 512 + c] = e2 * inv;
    }
}

// ---------- K5: combine (precomputed gates): outT[b,s,c] = sum_j g_j * x_j (bf16) ----------
__global__ __launch_bounds__(256) void combine_g(
    const unsigned short* __restrict__ y, const float* __restrict__ g,
    unsigned short* __restrict__ outT)
{
    int b = blockIdx.y;
    int t = threadIdx.x;
    int w = blockIdx.x * 4 + (t >> 6);
    int c8 = (t & 63) * 8;
    int q = c8 >> 7;
    int dw1 = (q == 0) ? -1 : (q == 1) ? 1 : 0;
    int dh1 = (q == 2) ? -1 : (q == 3) ? 1 : 0;
    int dh2 = (q == 0) ? -1 : (q == 1) ? 1 : 0;
    int dw2 = (q == 2) ? -1 : (q == 3) ? 1 : 0;
    float g0[8], g1[8], g2[8];
    {
        const float4* pa = (const float4*)(g + (b * 3 + 0) * 512 + c8);
        const float4* pb = (const float4*)(g + (b * 3 + 1) * 512 + c8);
        const float4* pc = (const float4*)(g + (b * 3 + 2) * 512 + c8);
        *(float4*)&g0[0] = pa[0]; *(float4*)&g0[4] = pa[1];
        *(float4*)&g1[0] = pb[0]; *(float4*)&g1[4] = pb[1];
        *(float4*)&g2[0] = pc[0]; *(float4*)&g2[4] = pc[1];
    }
    int w1i = min(max(w + dw1, 0), 31);
    int w2i = min(max(w + dw2, 0), 31);
    size_t base = (size_t)b * S_;
    for (int h = 0; h < 32; h++) {
        int h1i = min(max(h + dh1, 0), 31);
        int h2i = min(max(h + dh2, 0), 31);
        uint4 u1 = *(const uint4*)&y[(base + w1i * 32 + h1i) * N1 + c8];
        uint4 u2 = *(const uint4*)&y[(base + w2i * 32 + h2i) * N1 + 512 + c8];
        uint4 u3 = *(const uint4*)&y[(base + w * 32 + h) * N1 + 1024 + c8];
        unsigned int p[4];
        const unsigned int* a1 = &u1.x;
        const unsigned int* a2 = &u2.x;
        const unsigned int* a3 = &u3.x;
#pragma unroll
        for (int k = 0; k < 4; k++) {
            int j = k * 2;
            float lo = g0[j] * b2f(a1[k]) + g1[j] * b2f(a2[k]) + g2[j] * b2f(a3[k]);
            float hi = g0[j + 1] * b2f(a1[k] >> 16) + g1[j + 1] * b2f(a2[k] >> 16) + g2[j + 1] * b2f(a3[k] >> 16);
            p[k] = (unsigned int)f2b(lo) | ((unsigned int)f2b(hi) << 16);
        }
        *(uint4*)&outT[(base + w * 32 + h) * 512 + c8] = make_uint4(p[0], p[1], p[2], p[3]);
    }
}

// ---------- K6: GEMM2 out = outT . w2^T + b2, transposed f32 epilogue ----------
__global__ __launch_bounds__(256) void gemm2(
    const unsigned short* __restrict__ A,
    const unsigned short* __restrict__ Wt,
    const float* __restrict__ bias,
    float* __restrict__ Z)
{
    const int K = 512;
    __shared__ __align__(16) unsigned short As[128 * 32]; // 8 KB, 64B rows
    __shared__ __align__(16) unsigned short Bs[128 * 32];
    int m0 = blockIdx.x * 128;
    int n0 = blockIdx.y * 128;
    int tid = threadIdx.x;
    int lane = tid & 63, wid = tid >> 6;
    int wm = (wid >> 1) * 64, wn = (wid & 1) * 64;
    int quad = lane >> 4, l16 = lane & 15;
    int ch0 = wid * 128 + lane;
    const unsigned short* Ab = A + (size_t)m0 * K;
    const unsigned short* Bb = Wt + (size_t)n0 * K;

    f32x4 acc[4][4] = {};

    for (int kt = 0; kt < K; kt += 32) {
        __syncthreads();
#pragma unroll
        for (int i = 0; i < 2; i++) {
            int ch = ch0 + i * 64;
            int m = ch >> 2, kc = ch & 3;
            size_t go = (size_t)m * K + kt + kc * 8;
            gl_lds16(Ab + go, &As[ch * 8]);
            gl_lds16(Bb + go, &Bs[ch * 8]);
        }
        __syncthreads();
        bf16x8 af[4], bfr[4];
#pragma unroll
        for (int t = 0; t < 4; t++) {
            af[t]  = *(const bf16x8*)&As[(wm + t * 16 + l16) * 32 + quad * 8];
            bfr[t] = *(const bf16x8*)&Bs[(wn + t * 16 + l16) * 32 + quad * 8];
        }
#pragma unroll
        for (int mt = 0; mt < 4; mt++)
#pragma unroll
            for (int nt = 0; nt < 4; nt++)
                acc[mt][nt] = __builtin_amdgcn_mfma_f32_16x16x32_bf16(af[mt], bfr[nt], acc[mt][nt], 0, 0, 0);
    }

    // transposed f32 epilogue: out[(b*512+n)*1024 + s], float4 along s
#pragma unroll
    for (int mt = 0; mt < 4; mt++) {
#pragma unroll
        for (int nt = 0; nt < 4; nt++) {
            int n = n0 + wn + nt * 16 + l16;
            float bv = bias[n];
            int mbase = m0 + wm + mt * 16 + quad * 4;
            int b = mbase >> 10;
            int s = mbase & 1023;
            float4 v = make_float4(acc[mt][nt][0] + bv, acc[mt][nt][1] + bv,
                                   acc[mt][nt][2] + bv, acc[mt][nt][3] + bv);
            *(float4*)(&Z[((size_t)(b * 512 + n)) * 1024 + s]) = v;
        }
    }
}

extern "C" void kernel_launch(void* const* d_in, const int* in_sizes, int n_in,
                              void* d_out, int out_size, void* d_ws, size_t ws_size,
                              hipStream_t stream) {
    const float* x  = (const float*)d_in[0];
    const float* w1 = (const float*)d_in[1];
    const float* b1 = (const float*)d_in[2];
    const float* wa = (const float*)d_in[3];
    const float* ba = (const float*)d_in[4];
    const float* wb = (const float*)d_in[5];
    const float* bb = (const float*)d_in[6];
    const float* w2 = (const float*)d_in[7];
    const float* b2 = (const float*)d_in[8];
    float* out = (float*)d_out;

    char* ws = (char*)d_ws;
    unsigned short* xT   = (unsigned short*)(ws);              // 16 MB (dead after gemm1)
    unsigned short* outT = (unsigned short*)(ws);              // aliases xT
    unsigned short* w1b  = (unsigned short*)(ws + 16777216);   // 1.5 MB
    unsigned short* w2b  = (unsigned short*)(ws + 18350080);   // 0.5 MB
    unsigned short* y    = (unsigned short*)(ws + 18874368);   // 48 MB: (B,S,3C) bf16
    float* sums          = (float*)(ws + 69206016);            // 5 x 96 KB: T,H0,H31,C0,C31
    float* h_buf         = (float*)(ws + 69697536);            // 32 KB
    float* g_buf         = (float*)(ws + 69730304);            // 96 KB: (16,3,512) f32

    float* Tsum = sums;
    float* H0   = sums + 24576;
    float* H31  = sums + 49152;
    float* C0   = sums + 73728;
    float* C31  = sums + 98304;

    prep_all<<<dim3(9336), dim3(256), 0, stream>>>(x, xT, w1, w2, w1b, w2b, sums);
    gemm1<<<dim3(128, 12), dim3(256), 0, stream>>>(
        xT, w1b, b1, y, Tsum, H0, H31, C0, C31);
    mlp_layer1<<<dim3(2048), dim3(256), 0, stream>>>(sums, wa, ba, h_buf);
    mlp2_gate<<<dim3(128), dim3(256), 0, stream>>>(h_buf, wb, bb, g_buf);
    combine_g<<<dim3(8, 16), dim3(256), 0, stream>>>(y, g_buf, outT);
    gemm2<<<dim3(128, 4), dim3(256), 0, stream>>>(outT, w2b, b2, out);
}

// Round 9
// 194.446 us; speedup vs baseline: 1.0322x; 1.0140x over previous
//
#include <hip/hip_runtime.h>
#include <stdint.h>

typedef __bf16 bf16x8 __attribute__((ext_vector_type(8)));
typedef float f32x4 __attribute__((ext_vector_type(4)));

#define B_ 16
#define C_ 512
#define S_ 1024   // W*H = 32*32
#define N1 1536   // 3C

// ---------- bf16 helpers (manual RNE) ----------
__device__ inline unsigned short f2b(float f) {
    unsigned int u = __builtin_bit_cast(unsigned int, f);
    unsigned int lsb = (u >> 16) & 1u;
    u += 0x7fffu + lsb;
    return (unsigned short)(u >> 16);
}
__device__ inline float b2f(unsigned int s) {
    unsigned int u = (s & 0xffffu) << 16;
    return __builtin_bit_cast(float, u);
}

// ---------- K1: transpose_convert_x + weight convert + sums zero (merged) ----------
__global__ __launch_bounds__(256) void prep_all(
    const float* __restrict__ x, unsigned short* __restrict__ xT,
    const float* __restrict__ w1, const float* __restrict__ w2,
    unsigned short* __restrict__ w1b, unsigned short* __restrict__ w2b,
    float* __restrict__ sums)
{
    int bid = blockIdx.x;
    int t = threadIdx.x;
    if (bid < 8192) {
        __shared__ float tile[32][33];
        int bx = bid & 31;          // s-tile
        int by = (bid >> 5) & 15;   // c-tile
        int bz = bid >> 9;          // batch
        int c0 = by * 32;
        int s0 = bx * 32;
        int tx = t & 31, ty = t >> 5; // (32,8)
        const float* xp = x + ((size_t)bz * C_ + c0) * S_ + s0;
#pragma unroll
        for (int i = 0; i < 4; i++)
            tile[ty + i * 8][tx] = xp[(size_t)(ty + i * 8) * S_ + tx];
        __syncthreads();
        unsigned short* op = xT + ((size_t)bz * S_ + s0) * C_ + c0;
#pragma unroll
        for (int i = 0; i < 4; i++)
            op[(size_t)(ty + i * 8) * C_ + tx] = f2b(tile[tx][ty + i * 8]);
    } else {
        int i = (bid - 8192) * 256 + t;
        if (i < 196608) {
            float4 v = ((const float4*)w1)[i];
            ((ushort4*)w1b)[i] = make_ushort4(f2b(v.x), f2b(v.y), f2b(v.z), f2b(v.w));
        } else if (i < 262144) {
            int j = i - 196608;
            float4 v = ((const float4*)w2)[j];
            ((ushort4*)w2b)[j] = make_ushort4(f2b(v.x), f2b(v.y), f2b(v.z), f2b(v.w));
        } else if (i < 292864) {
            int j = i - 262144;
            ((float4*)sums)[j] = make_float4(0.f, 0.f, 0.f, 0.f);
        }
    }
}

// shift tables per quarter q = c>>7:
// x1: dw = {-1,+1,0,0}[q], dh = {0,0,-1,+1}[q]   (channels [0,512) of y)
// x2: dh = {-1,+1,0,0}[q], dw = {0,0,-1,+1}[q]   (channels [512,1024))
// x3: no shift                                    (channels [1024,1536))

// ---------- K2: GEMM1 y = xT . w1^T + b1, with fused a-sum planes ----------
// VGPR-prefetch K-loop: global_load -> regs issued AFTER the barrier (so the
// barrier never drains them); ds_write consumes them next iter after ~600cyc
// of compute has covered the load latency. LDS double-buffered, ONE barrier/iter.
__global__ __launch_bounds__(256) void gemm1(
    const unsigned short* __restrict__ A,
    const unsigned short* __restrict__ Wt,
    const float* __restrict__ bias,
    unsigned short* __restrict__ Y,
    float* __restrict__ Tsum, float* __restrict__ H0, float* __restrict__ H31,
    float* __restrict__ C0, float* __restrict__ C31)
{
    const int K = 512;
    const int N = 1536;
    __shared__ __align__(16) unsigned short As[2][128 * 32]; // 2 x 8 KB
    __shared__ __align__(16) unsigned short Bs[2][128 * 32];
    int m0 = blockIdx.x * 128;
    int n0 = blockIdx.y * 128;
    int tid = threadIdx.x;
    int lane = tid & 63, wid = tid >> 6;
    int wm = (wid >> 1) * 64, wn = (wid & 1) * 64;
    int quad = lane >> 4, l16 = lane & 15;
    int ch1 = wid * 128 + lane;
    int ch2 = ch1 + 64;
    int lo1 = ch1 * 8, lo2 = ch2 * 8;                      // LDS short-offsets
    const unsigned short* pA1 = A + (size_t)m0 * K + (size_t)(ch1 >> 2) * K + (ch1 & 3) * 8;
    const unsigned short* pA2 = A + (size_t)m0 * K + (size_t)(ch2 >> 2) * K + (ch2 & 3) * 8;
    const unsigned short* pB1 = Wt + (size_t)n0 * K + (size_t)(ch1 >> 2) * K + (ch1 & 3) * 8;
    const unsigned short* pB2 = Wt + (size_t)n0 * K + (size_t)(ch2 >> 2) * K + (ch2 & 3) * 8;

    f32x4 acc[4][4] = {};

    // prologue: prefetch tile 0
    uint4 ra0 = *(const uint4*)(pA1);
    uint4 ra1 = *(const uint4*)(pA2);
    uint4 rb0 = *(const uint4*)(pB1);
    uint4 rb1 = *(const uint4*)(pB2);

    for (int it = 0; it < 16; it++) {
        unsigned short* Ac = &As[it & 1][0];
        unsigned short* Bc = &Bs[it & 1][0];
        // commit prefetched tile to LDS (waits its own vmcnt, already covered)
        *(uint4*)&Ac[lo1] = ra0;
        *(uint4*)&Ac[lo2] = ra1;
        *(uint4*)&Bc[lo1] = rb0;
        *(uint4*)&Bc[lo2] = rb1;
        __syncthreads();
        // prefetch next tile — issued after the barrier, flies during compute
        if (it < 15) {
            int kt = (it + 1) * 32;
            ra0 = *(const uint4*)(pA1 + kt);
            ra1 = *(const uint4*)(pA2 + kt);
            rb0 = *(const uint4*)(pB1 + kt);
            rb1 = *(const uint4*)(pB2 + kt);
        }
        bf16x8 af[4], bfr[4];
#pragma unroll
        for (int t = 0; t < 4; t++) {
            af[t]  = *(const bf16x8*)&Ac[(wm + t * 16 + l16) * 32 + quad * 8];
            bfr[t] = *(const bf16x8*)&Bc[(wn + t * 16 + l16) * 32 + quad * 8];
        }
#pragma unroll
        for (int mt = 0; mt < 4; mt++)
#pragma unroll
            for (int nt = 0; nt < 4; nt++)
                acc[mt][nt] = __builtin_amdgcn_mfma_f32_16x16x32_bf16(af[mt], bfr[nt], acc[mt][nt], 0, 0, 0);
        // no trailing barrier needed: next iter writes the OTHER buffer;
        // reads of that buffer (iter-1) are separated by this iter's barrier.
    }

    // ---- write y (bf16) ----
#pragma unroll
    for (int mt = 0; mt < 4; mt++) {
#pragma unroll
        for (int nt = 0; nt < 4; nt++) {
            int n = n0 + wn + nt * 16 + l16;
            float bv = bias[n];
            int mbase = m0 + wm + mt * 16 + quad * 4;
#pragma unroll
            for (int r = 0; r < 4; r++)
                Y[(size_t)(mbase + r) * N + n] = f2b(acc[mt][nt][r] + bv);
        }
    }

    // ---- fused a-sum accumulators ----
    // m_local = wm + mt*16 + quad*4 + r; h = m_local&31; w = wlo + (m_local>>5)
    {
        int b = m0 >> 10;
        int wlo = (m0 & 1023) >> 5; // first of 4 w-rows in this block
#pragma unroll
        for (int nt = 0; nt < 4; nt++) {
            int n = n0 + wn + nt * 16 + l16;
            float bv = bias[n];
            float tT = 0.f;
#pragma unroll
            for (int mt = 0; mt < 4; mt++)
#pragma unroll
                for (int r = 0; r < 4; r++) tT += acc[mt][nt][r] + bv;
            tT += __shfl_xor(tT, 16);
            tT += __shfl_xor(tT, 32);
            if (quad == 0) {
                atomicAdd(&Tsum[b * 1536 + n], tT);
                float th0 = acc[0][nt][0] + acc[2][nt][0] + 2.f * bv; // h==0 rows
                atomicAdd(&H0[b * 1536 + n], th0);
            }
            if (quad == 3) {
                float th31 = acc[1][nt][3] + acc[3][nt][3] + 2.f * bv; // h==31 rows
                atomicAdd(&H31[b * 1536 + n], th31);
            }
            if (wlo == 0 && wm == 0) { // w==0 slice: m_local < 32 -> mt 0,1
                float tc = 0.f;
#pragma unroll
                for (int mt = 0; mt < 2; mt++)
#pragma unroll
                    for (int r = 0; r < 4; r++) tc += acc[mt][nt][r] + bv;
                tc += __shfl_xor(tc, 16);
                tc += __shfl_xor(tc, 32);
                if (quad == 0) atomicAdd(&C0[b * 1536 + n], tc);
            }
            if (wlo == 28 && wm == 64) { // w==31 slice: m_local >= 96 -> mt 2,3
                float tc = 0.f;
#pragma unroll
                for (int mt = 2; mt < 4; mt++)
#pragma unroll
                    for (int r = 0; r < 4; r++) tc += acc[mt][nt][r] + bv;
                tc += __shfl_xor(tc, 16);
                tc += __shfl_xor(tc, 32);
                if (quad == 0) atomicAdd(&C31[b * 1536 + n], tc);
            }
        }
    }
}

// ---------- K3: layer1 (reconstruct a from sum planes, wave-dot, gelu) ----------
__global__ __launch_bounds__(256) void mlp_layer1(
    const float* __restrict__ sums, const float* __restrict__ wa,
    const float* __restrict__ ba, float* __restrict__ h)
{
    __shared__ float sa[512];
    int b = blockIdx.x >> 7;
    int t = threadIdx.x;
    const float* Tp   = sums;
    const float* H0p  = sums + 24576;
    const float* H31p = sums + 49152;
    const float* C0p  = sums + 73728;
    const float* C31p = sums + 98304;
#pragma unroll
    for (int j = 0; j < 2; j++) {
        int c = t + j * 256;
        int q = c >> 7;
        int n1 = b * 1536 + c;
        float t123 = Tp[n1] + Tp[n1 + 512] + Tp[n1 + 1024];
        float sC1 = C0p[n1] - C31p[n1];
        float sH1 = H0p[n1] - H31p[n1];
        float sC2 = C0p[n1 + 512] - C31p[n1 + 512];
        float sH2 = H0p[n1 + 512] - H31p[n1 + 512];
        float e = (q < 2) ? (sC1 + sH2) : (sH1 + sC2);
        sa[c] = t123 + ((q & 1) ? -e : e);
    }
    __syncthreads();
    int lane = t & 63, wid = t >> 6;
    int o = (blockIdx.x & 127) * 4 + wid;
    const float4* wr = (const float4*)(wa + (size_t)o * 512);
    float4 w0 = wr[lane * 2], w1v = wr[lane * 2 + 1];
    float4 a0 = ((const float4*)sa)[lane * 2], a1 = ((const float4*)sa)[lane * 2 + 1];
    float dot = w0.x * a0.x + w0.y * a0.y + w0.z * a0.z + w0.w * a0.w
              + w1v.x * a1.x + w1v.y * a1.y + w1v.z * a1.z + w1v.w * a1.w;
#pragma unroll
    for (int off = 32; off; off >>= 1) dot += __shfl_down(dot, off);
    if (lane == 0) {
        float v = dot + ba[o];
        h[b * 512 + o] = 0.5f * v * (1.0f + erff(v * 0.7071067811865475f));
    }
}

// ---------- K4: layer2 + softmax gate, o-major (wave owns channel c, all 16 b) ----------
__global__ __launch_bounds__(256) void mlp2_gate(
    const float* __restrict__ h, const float* __restrict__ wb,
    const float* __restrict__ bb, float* __restrict__ g)
{
    __shared__ float hat_s[4][3][16];
    int wv = threadIdx.x >> 6, lane = threadIdx.x & 63;
    int c = blockIdx.x * 4 + wv;
    float4 wr[3][2];
    float bbv[3];
#pragma unroll
    for (int j = 0; j < 3; j++) {
        const float4* p = (const float4*)(wb + (size_t)(j * 512 + c) * 512 + lane * 8);
        wr[j][0] = p[0]; wr[j][1] = p[1];
        bbv[j] = bb[j * 512 + c];
    }
    for (int b = 0; b < 16; b++) {
        const float4* hp = (const float4*)(h + b * 512 + lane * 8);
        float4 h0 = hp[0], h1 = hp[1];
        float d[3];
#pragma unroll
        for (int j = 0; j < 3; j++) {
            d[j] = wr[j][0].x * h0.x + wr[j][0].y * h0.y + wr[j][0].z * h0.z + wr[j][0].w * h0.w
                 + wr[j][1].x * h1.x + wr[j][1].y * h1.y + wr[j][1].z * h1.z + wr[j][1].w * h1.w;
#pragma unroll
            for (int off = 32; off; off >>= 1) d[j] += __shfl_down(d[j], off);
        }
        if (lane == 0) {
#pragma unroll
            for (int j = 0; j < 3; j++) hat_s[wv][j][b] = d[j] + bbv[j];
        }
    }
    __syncthreads();
    if (lane < 16) {
        int b = lane;
        float h0 = hat_s[wv][0][b], h1 = hat_s[wv][1][b], h2 = hat_s[wv][2][b];
        float mx = fmaxf(h0, fmaxf(h1, h2));
        float e0 = __expf(h0 - mx), e1 = __expf(h1 - mx), e2 = __expf(h2 - mx);
        float inv = 1.0f / (e0 + e1 + e2);
        g[(b * 3 + 0) * 512 + c] = e0 * inv;
        g[(b * 3 + 1) * 512 + c] = e1 * inv;
        g[(b * 3 + 2) * 512 + c] = e2 * inv;
    }
}

// ---------- K5: combine (precomputed gates): outT[b,s,c] = sum_j g_j * x_j (bf16) ----------
__global__ __launch_bounds__(256) void combine_g(
    const unsigned short* __restrict__ y, const float* __restrict__ g,
    unsigned short* __restrict__ outT)
{
    int b = blockIdx.y;
    int t = threadIdx.x;
    int w = blockIdx.x * 4 + (t >> 6);
    int c8 = (t & 63) * 8;
    int q = c8 >> 7;
    int dw1 = (q == 0) ? -1 : (q == 1) ? 1 : 0;
    int dh1 = (q == 2) ? -1 : (q == 3) ? 1 : 0;
    int dh2 = (q == 0) ? -1 : (q == 1) ? 1 : 0;
    int dw2 = (q == 2) ? -1 : (q == 3) ? 1 : 0;
    float g0[8], g1[8], g2[8];
    {
        const float4* pa = (const float4*)(g + (b * 3 + 0) * 512 + c8);
        const float4* pb = (const float4*)(g + (b * 3 + 1) * 512 + c8);
        const float4* pc = (const float4*)(g + (b * 3 + 2) * 512 + c8);
        *(float4*)&g0[0] = pa[0]; *(float4*)&g0[4] = pa[1];
        *(float4*)&g1[0] = pb[0]; *(float4*)&g1[4] = pb[1];
        *(float4*)&g2[0] = pc[0]; *(float4*)&g2[4] = pc[1];
    }
    int w1i = min(max(w + dw1, 0), 31);
    int w2i = min(max(w + dw2, 0), 31);
    size_t base = (size_t)b * S_;
    for (int h = 0; h < 32; h++) {
        int h1i = min(max(h + dh1, 0), 31);
        int h2i = min(max(h + dh2, 0), 31);
        uint4 u1 = *(const uint4*)&y[(base + w1i * 32 + h1i) * N1 + c8];
        uint4 u2 = *(const uint4*)&y[(base + w2i * 32 + h2i) * N1 + 512 + c8];
        uint4 u3 = *(const uint4*)&y[(base + w * 32 + h) * N1 + 1024 + c8];
        unsigned int p[4];
        const unsigned int* a1 = &u1.x;
        const unsigned int* a2 = &u2.x;
        const unsigned int* a3 = &u3.x;
#pragma unroll
        for (int k = 0; k < 4; k++) {
            int j = k * 2;
            float lo = g0[j] * b2f(a1[k]) + g1[j] * b2f(a2[k]) + g2[j] * b2f(a3[k]);
            float hi = g0[j + 1] * b2f(a1[k] >> 16) + g1[j + 1] * b2f(a2[k] >> 16) + g2[j + 1] * b2f(a3[k] >> 16);
            p[k] = (unsigned int)f2b(lo) | ((unsigned int)f2b(hi) << 16);
        }
        *(uint4*)&outT[(base + w * 32 + h) * 512 + c8] = make_uint4(p[0], p[1], p[2], p[3]);
    }
}

// ---------- K6: GEMM2 out = outT . w2^T + b2 (same VGPR-prefetch K-loop) ----------
__global__ __launch_bounds__(256) void gemm2(
    const unsigned short* __restrict__ A,
    const unsigned short* __restrict__ Wt,
    const float* __restrict__ bias,
    float* __restrict__ Z)
{
    const int K = 512;
    __shared__ __align__(16) unsigned short As[2][128 * 32];
    __shared__ __align__(16) unsigned short Bs[2][128 * 32];
    int m0 = blockIdx.x * 128;
    int n0 = blockIdx.y * 128;
    int tid = threadIdx.x;
    int lane = tid & 63, wid = tid >> 6;
    int wm = (wid >> 1) * 64, wn = (wid & 1) * 64;
    int quad = lane >> 4, l16 = lane & 15;
    int ch1 = wid * 128 + lane;
    int ch2 = ch1 + 64;
    int lo1 = ch1 * 8, lo2 = ch2 * 8;
    const unsigned short* pA1 = A + (size_t)m0 * K + (size_t)(ch1 >> 2) * K + (ch1 & 3) * 8;
    const unsigned short* pA2 = A + (size_t)m0 * K + (size_t)(ch2 >> 2) * K + (ch2 & 3) * 8;
    const unsigned short* pB1 = Wt + (size_t)n0 * K + (size_t)(ch1 >> 2) * K + (ch1 & 3) * 8;
    const unsigned short* pB2 = Wt + (size_t)n0 * K + (size_t)(ch2 >> 2) * K + (ch2 & 3) * 8;

    f32x4 acc[4][4] = {};

    uint4 ra0 = *(const uint4*)(pA1);
    uint4 ra1 = *(const uint4*)(pA2);
    uint4 rb0 = *(const uint4*)(pB1);
    uint4 rb1 = *(const uint4*)(pB2);

    for (int it = 0; it < 16; it++) {
        unsigned short* Ac = &As[it & 1][0];
        unsigned short* Bc = &Bs[it & 1][0];
        *(uint4*)&Ac[lo1] = ra0;
        *(uint4*)&Ac[lo2] = ra1;
        *(uint4*)&Bc[lo1] = rb0;
        *(uint4*)&Bc[lo2] = rb1;
        __syncthreads();
        if (it < 15) {
            int kt = (it + 1) * 32;
            ra0 = *(const uint4*)(pA1 + kt);
            ra1 = *(const uint4*)(pA2 + kt);
            rb0 = *(const uint4*)(pB1 + kt);
            rb1 = *(const uint4*)(pB2 + kt);
        }
        bf16x8 af[4], bfr[4];
#pragma unroll
        for (int t = 0; t < 4; t++) {
            af[t]  = *(const bf16x8*)&Ac[(wm + t * 16 + l16) * 32 + quad * 8];
            bfr[t] = *(const bf16x8*)&Bc[(wn + t * 16 + l16) * 32 + quad * 8];
        }
#pragma unroll
        for (int mt = 0; mt < 4; mt++)
#pragma unroll
            for (int nt = 0; nt < 4; nt++)
                acc[mt][nt] = __builtin_amdgcn_mfma_f32_16x16x32_bf16(af[mt], bfr[nt], acc[mt][nt], 0, 0, 0);
    }

    // transposed f32 epilogue: out[(b*512+n)*1024 + s], float4 along s
#pragma unroll
    for (int mt = 0; mt < 4; mt++) {
#pragma unroll
        for (int nt = 0; nt < 4; nt++) {
            int n = n0 + wn + nt * 16 + l16;
            float bv = bias[n];
            int mbase = m0 + wm + mt * 16 + quad * 4;
            int b = mbase >> 10;
            int s = mbase & 1023;
            float4 v = make_float4(acc[mt][nt][0] + bv, acc[mt][nt][1] + bv,
                                   acc[mt][nt][2] + bv, acc[mt][nt][3] + bv);
            *(float4*)(&Z[((size_t)(b * 512 + n)) * 1024 + s]) = v;
        }
    }
}

extern "C" void kernel_launch(void* const* d_in, const int* in_sizes, int n_in,
                              void* d_out, int out_size, void* d_ws, size_t ws_size,
                              hipStream_t stream) {
    const float* x  = (const float*)d_in[0];
    const float* w1 = (const float*)d_in[1];
    const float* b1 = (const float*)d_in[2];
    const float* wa = (const float*)d_in[3];
    const float* ba = (const float*)d_in[4];
    const float* wb = (const float*)d_in[5];
    const float* bb = (const float*)d_in[6];
    const float* w2 = (const float*)d_in[7];
    const float* b2 = (const float*)d_in[8];
    float* out = (float*)d_out;

    char* ws = (char*)d_ws;
    unsigned short* xT   = (unsigned short*)(ws);              // 16 MB (dead after gemm1)
    unsigned short* outT = (unsigned short*)(ws);              // aliases xT
    unsigned short* w1b  = (unsigned short*)(ws + 16777216);   // 1.5 MB
    unsigned short* w2b  = (unsigned short*)(ws + 18350080);   // 0.5 MB
    unsigned short* y    = (unsigned short*)(ws + 18874368);   // 48 MB: (B,S,3C) bf16
    float* sums          = (float*)(ws + 69206016);            // 5 x 96 KB: T,H0,H31,C0,C31
    float* h_buf         = (float*)(ws + 69697536);            // 32 KB
    float* g_buf         = (float*)(ws + 69730304);            // 96 KB: (16,3,512) f32

    float* Tsum = sums;
    float* H0   = sums + 24576;
    float* H31  = sums + 49152;
    float* C0   = sums + 73728;
    float* C31  = sums + 98304;

    prep_all<<<dim3(9336), dim3(256), 0, stream>>>(x, xT, w1, w2, w1b, w2b, sums);
    gemm1<<<dim3(128, 12), dim3(256), 0, stream>>>(
        xT, w1b, b1, y, Tsum, H0, H31, C0, C31);
    mlp_layer1<<<dim3(2048), dim3(256), 0, stream>>>(sums, wa, ba, h_buf);
    mlp2_gate<<<dim3(128), dim3(256), 0, stream>>>(h_buf, wb, bb, g_buf);
    combine_g<<<dim3(8, 16), dim3(256), 0, stream>>>(y, g_buf, outT);
    gemm2<<<dim3(128, 4), dim3(256), 0, stream>>>(outT, w2b, b2, out);
}